// Round 10
// baseline (414.050 us; speedup 1.0000x reference)
//
#include <hip/hip_runtime.h>

// LapCluster MI355X — round 19: double-buffered f3 DMA (kmid/k3).
// r18 post-mortem: WIN (416->388). DMA stage-in + linear dump confirmed the
// mechanism: remove instructions from the serial per-tile chain. kmid now
// <84us (out of top-5), k0 top at ~84 w/ Mfma 17.5%. Clean traffic
// (FETCH 123MB, SGPR 112 — no r16 ghost).
// This round, same mechanism: hide the stage-in DMA completion wait (~500-900
// cyc at each B1) by double-buffering the f3 LDS image — issue tile t+1's DMA
// right after B1 of tile t into the other buffer; tile-t compute hides it.
// kmid fits via the r15-17-verified A-in-F-cols-0..63 trick (A planes
// deleted; +1 barrier): LDS 65536+8192=73728 (2/CU). k3: 2x32768=65536
// (2/CU), old B4 redundant under dbuf -> 3 barriers/tile. k0 unchanged.
// Watch: kmid SGPR (112 good / 32 = r16 compile-ghost -> revert), FETCH
// ~123MB, kmid dur 80->68-75, k3 -6-10us, total 388->~360.

typedef __attribute__((ext_vector_type(8))) short bf16x8;
typedef __attribute__((ext_vector_type(4))) float f32x4;
typedef __attribute__((ext_vector_type(4))) unsigned u32x4;
typedef __attribute__((ext_vector_type(4))) float f32x4v;

#define MFMA16(a, b, c) __builtin_amdgcn_mfma_f32_16x16x32_bf16((a), (b), (c), 0, 0, 0)

#define TPB 512
#define PT 64
#define NPTS 131072
#define NC 16
#define TILES 4
#define NBLK 512         // 64 blocks/batch

#define FSB 128          // F plane stride (shorts) — bank-swizzled, image-linear
#define ASB 72           // A64 plane stride (k0 only; padded, unswizzled)
#define XSB 40           // x staging stride (k0 only; padded, unswizzled)
#define TILE_BYTES (2 * PT * FSB * 2)   // 32768 B per f3 tile image
#define FPLANE (PT * FSB)               // shorts per plane

// frag arena units (1 unit = 64 lanes * 8 dwords: [0..3]=hi frag, [4..7]=lo)
#define U_F256 0
#define U_W1_0 16
#define U_W2_0 48
#define U_W3_0 64
#define U_W1_1 96
#define U_W2_1 112
#define U_W3_1 128
#define U_W1_2 160
#define U_W2_2 176
#define U_W3_2 192
#define U_O1   224
#define U_O2   256
#define N_UNITS 288

// XOR bank swizzle within a row (F planes only): bijective per row, keeps
// 16B alignment of 8-short groups. Verified r16-r18.
__device__ __forceinline__ int swz(int row, int col) {
  return col ^ ((row & 7) << 3);
}

__device__ __forceinline__ f32x4 relu4(f32x4 a) {
#pragma unroll
  for (int r = 0; r < 4; ++r) a[r] = fmaxf(a[r], 0.f);
  return a;
}

// swizzled fragment read from an F plane (FSB)
__device__ __forceinline__ bf16x8 afragF(const short* plane, int mt, int ks) {
  const int lane = threadIdx.x & 63;
  const int row = mt * 16 + (lane & 15);
  const int col = ks * 32 + (lane >> 4) * 8;
  return *reinterpret_cast<const bf16x8*>(plane + row * FSB + swz(row, col));
}

// plain strided fragment read (X/A planes, k0 only)
__device__ __forceinline__ bf16x8 afragS(const short* plane, int stride, int mt, int ks) {
  const int lane = threadIdx.x & 63;
  return *reinterpret_cast<const bf16x8*>(
      plane + (mt * 16 + (lane & 15)) * stride + ks * 32 + (lane >> 4) * 8);
}

__device__ __forceinline__ void bfrag(const unsigned* __restrict__ arena, int unit,
                                      bf16x8& h, bf16x8& l) {
  const bf16x8* p = reinterpret_cast<const bf16x8*>(
      arena + ((size_t)unit * 64 + (threadIdx.x & 63)) * 8);
  h = p[0];
  l = p[1];
}

// write relu'd D (4 regs = pts mt*16 + quad*4 + r) into swizzled F planes
__device__ __forceinline__ void store_planesF(short* hp, short* lp,
                                              int mt, int n, f32x4 d) {
  const int m0 = mt * 16 + ((threadIdx.x & 63) >> 4) * 4;
#pragma unroll
  for (int r = 0; r < 4; ++r) {
    const int row = m0 + r;
    const int c = swz(row, n);
    unsigned uv = __float_as_uint(d[r]);
    unsigned hm = uv & 0xFFFF0000u;
    float lo = d[r] - __uint_as_float(hm);
    hp[row * FSB + c] = (short)(hm >> 16);
    lp[row * FSB + c] = (short)(__float_as_uint(lo) >> 16);
  }
}

// plain strided store (A planes, k0 only)
__device__ __forceinline__ void store_planesS(short* hp, short* lp, int stride,
                                              int mt, int n, f32x4 d) {
  const int m0 = mt * 16 + ((threadIdx.x & 63) >> 4) * 4;
#pragma unroll
  for (int r = 0; r < 4; ++r) {
    unsigned uv = __float_as_uint(d[r]);
    unsigned hm = uv & 0xFFFF0000u;
    float lo = d[r] - __uint_as_float(hm);
    hp[(m0 + r) * stride + n] = (short)(hm >> 16);
    lp[(m0 + r) * stride + n] = (short)(__float_as_uint(lo) >> 16);
  }
}

// ---- async global->LDS 16B (linear identity copy)
__device__ __forceinline__ void gl_lds16(const char* g, const char* l) {
  typedef __attribute__((address_space(1))) const unsigned as1_u32;
  typedef __attribute__((address_space(3))) unsigned as3_u32;
  as1_u32* gp = reinterpret_cast<as1_u32*>((unsigned long long)g);
  as3_u32* lp = reinterpret_cast<as3_u32*>((unsigned)(unsigned long long)l);
  __builtin_amdgcn_global_load_lds(gp, lp, 16, 0, 0);
}

// stage-in: f3g tile image -> Fboth, 32 x 1KB wave-segments via DMA
__device__ __forceinline__ void stage_f3(const unsigned* __restrict__ f3g,
                                         int tile_idx, short* Fboth,
                                         int w, int lane) {
  const char* g = reinterpret_cast<const char*>(f3g) + (size_t)tile_idx * TILE_BYTES;
  const char* l = reinterpret_cast<const char*>(Fboth);
#pragma unroll
  for (int i = 0; i < 4; ++i) {
    const int seg = i * 8 + w;
    gl_lds16(g + seg * 1024 + lane * 16, l + seg * 1024);
  }
}

// dump-out: Fboth -> f3g tile image, linear coalesced uint4 copy
__device__ __forceinline__ void dump_f3(unsigned* __restrict__ f3g, int tile_idx,
                                        const short* Fboth, int tid) {
  u32x4* dst = reinterpret_cast<u32x4*>(
      reinterpret_cast<char*>(f3g) + (size_t)tile_idx * TILE_BYTES);
  const u32x4* src = reinterpret_cast<const u32x4*>(Fboth);
#pragma unroll
  for (int i = 0; i < 4; ++i)
    dst[i * TPB + tid] = src[i * TPB + tid];
}

// ---- prep: split weights into fragment-ordered hi/lo bf16 arenas (unchanged)
__global__ void __launch_bounds__(64) prep_frags(
    const float* __restrict__ w_in, const float* __restrict__ w1,
    const float* __restrict__ w2, const float* __restrict__ w3,
    const float* __restrict__ wo1, const float* __restrict__ wo2,
    unsigned* __restrict__ arena) {
  const int unit = blockIdx.x;
  const int lane = threadIdx.x;
  const float* W; int KS, Klog, rs, u;
  if (unit < U_W1_0)      { W = w_in;                   u = unit - U_F256; KS = 1; Klog = 28;  rs = 28;  }
  else if (unit < U_W2_0) { W = w1;                     u = unit - U_W1_0; KS = 8; Klog = 256; rs = 256; }
  else if (unit < U_W3_0) { W = w2;                     u = unit - U_W2_0; KS = 2; Klog = 64;  rs = 64;  }
  else if (unit < U_W1_1) { W = w3;                     u = unit - U_W3_0; KS = 4; Klog = 128; rs = 128; }
  else if (unit < U_W2_1) { W = w1 + 64 * 256;          u = unit - U_W1_1; KS = 4; Klog = 128; rs = 256; }
  else if (unit < U_W3_1) { W = w2 + 128 * 64;          u = unit - U_W2_1; KS = 2; Klog = 64;  rs = 64;  }
  else if (unit < U_W1_2) { W = w3 + 128 * 128;         u = unit - U_W3_1; KS = 4; Klog = 128; rs = 128; }
  else if (unit < U_W2_2) { W = w1 + 2 * 64 * 256;      u = unit - U_W1_2; KS = 4; Klog = 128; rs = 256; }
  else if (unit < U_W3_2) { W = w2 + 2 * 128 * 64;      u = unit - U_W2_2; KS = 2; Klog = 64;  rs = 64;  }
  else if (unit < U_O1)   { W = w3 + 2 * 128 * 128;     u = unit - U_W3_2; KS = 4; Klog = 128; rs = 128; }
  else if (unit < U_O2)   { W = wo1;                    u = unit - U_O1;   KS = 4; Klog = 128; rs = 256; }
  else                    { W = wo2;                    u = unit - U_O2;   KS = 4; Klog = 128; rs = 128; }
  const int nt = u / KS, ks = u % KS;
  const int n = nt * 16 + (lane & 15);
  const int k0 = ks * 32 + (lane >> 4) * 8;
  unsigned hiD[4], loD[4];
#pragma unroll
  for (int d = 0; d < 4; ++d) {
    unsigned hu[2], lu[2];
#pragma unroll
    for (int e = 0; e < 2; ++e) {
      const int k = k0 + d * 2 + e;
      float v = (k < Klog) ? W[(size_t)n * rs + k] : 0.f;
      unsigned uv = __float_as_uint(v);
      unsigned hm = uv & 0xFFFF0000u;
      float lo = v - __uint_as_float(hm);
      hu[e] = hm >> 16;
      lu[e] = __float_as_uint(lo) >> 16;
    }
    hiD[d] = hu[0] | (hu[1] << 16);
    loD[d] = lu[0] | (lu[1] << 16);
  }
  unsigned* dst = arena + ((size_t)unit * 64 + lane) * 8;
  *reinterpret_cast<uint4*>(dst)     = make_uint4(hiD[0], hiD[1], hiD[2], hiD[3]);
  *reinterpret_cast<uint4*>(dst + 4) = make_uint4(loD[0], loD[1], loD[2], loD[3]);
}

// ---- per-batch poolc table (fp32) — unchanged
template<int O>
__global__ void __launch_bounds__(1024) pool_reduce_kern(
    const unsigned* __restrict__ part, const float* __restrict__ W,
    const float* __restrict__ bias, float* __restrict__ poolc_g) {
  __shared__ float pfL[2048];
  __shared__ float Wl[O * 129];
  const int tid = threadIdx.x;
  const int b = blockIdx.x;
  for (int i = tid; i < 2048; i += 1024) pfL[i] = __uint_as_float(part[b * 2048 + i]);
  for (int i = tid; i < O * 128; i += 1024) {
    const int o = i >> 7, k = i & 127;
    Wl[o * 129 + k] = W[o * 256 + 128 + k];
  }
  __syncthreads();
  constexpr int SH = (O == 64) ? 6 : 7;
  for (int e = tid; e < O * 16; e += 1024) {
    const int o = e & (O - 1);
    const int cl = e >> SH;
    float s = bias[o];
    const float* wr = &Wl[o * 129];
    const float* pr = &pfL[cl];
#pragma unroll 4
    for (int k = 0; k < 128; ++k) s = fmaf(wr[k], pr[k * 16], s);
    poolc_g[(size_t)b * (O * 16) + o * 16 + cl] = s;
  }
}

// ---- Stage 0: unchanged from r18 (x-staged directly, single F buffer)
__global__ void __launch_bounds__(TPB, 4) k0_kern(
    const float* __restrict__ x, const int* __restrict__ cls,
    const float* __restrict__ b_in, const float* __restrict__ b1,
    const float* __restrict__ b2, const float* __restrict__ b3,
    const unsigned* __restrict__ arena,
    unsigned* __restrict__ f3g, unsigned* __restrict__ part0) {
  __shared__ short Fboth[2 * PT * FSB];            // [hi 16KB][lo 16KB] image
  __shared__ short XA[PT * ASB * 2];               // x planes alias A64 planes
  __shared__ unsigned pool_s[128 * NC];
  short* Fhi = Fboth;  short* Flo = Fboth + FPLANE;
  short* Xhi = XA;  short* Xlo = XA + PT * XSB;
  short* Ahi = XA;  short* Alo = XA + PT * ASB;
  const int tid = threadIdx.x;
  const int lane = tid & 63, w = tid >> 6, l15 = lane & 15, quad = lane >> 4;
  const int b = blockIdx.x >> 6;
  const int Nt1 = w & 3, mh = w >> 2;
  for (int i = tid; i < 128 * NC; i += TPB) pool_s[i] = 0u;

  float biH[2];
#pragma unroll
  for (int c = 0; c < 2; ++c) biH[c] = b_in[c * 128 + w * 16 + l15];
  const float b1H = b1[Nt1 * 16 + l15];
  const float b2H = b2[w * 16 + l15];
  const float b3H = b3[w * 16 + l15];
  const int n1 = Nt1 * 16 + l15;
  const int n2 = w * 16 + l15;
  const int xpt = (tid < 448) ? tid / 7 : 0;
  const int xc4 = (tid < 448) ? (tid - xpt * 7) * 4 : 0;

  for (int t = 0; t < TILES; ++t) {
    const int tile_idx = blockIdx.x * TILES + t;
    const int tile0 = tile_idx * PT;
    if (tid < 448) {   // stage x hi/lo
      const f32x4v v = __builtin_nontemporal_load(
          reinterpret_cast<const f32x4v*>(x + (size_t)(tile0 + xpt) * 28 + xc4));
      unsigned h0 = __float_as_uint(v.x) & 0xFFFF0000u, h1 = __float_as_uint(v.y) & 0xFFFF0000u;
      unsigned h2 = __float_as_uint(v.z) & 0xFFFF0000u, h3 = __float_as_uint(v.w) & 0xFFFF0000u;
      uint2 hd, ld;
      hd.x = (h0 >> 16) | h1;
      hd.y = (h2 >> 16) | h3;
      ld.x = (__float_as_uint(v.x - __uint_as_float(h0)) >> 16) |
             (__float_as_uint(v.y - __uint_as_float(h1)) & 0xFFFF0000u);
      ld.y = (__float_as_uint(v.z - __uint_as_float(h2)) >> 16) |
             (__float_as_uint(v.w - __uint_as_float(h3)) & 0xFFFF0000u);
      *reinterpret_cast<uint2*>(&Xhi[xpt * XSB + xc4]) = hd;
      *reinterpret_cast<uint2*>(&Xlo[xpt * XSB + xc4]) = ld;
    } else {           // zero k pads 28..31 (region aliased by A64 last tile)
      const int p = tid - 448;
      *reinterpret_cast<uint2*>(&Xhi[p * XSB + 28]) = make_uint2(0u, 0u);
      *reinterpret_cast<uint2*>(&Xlo[p * XSB + 28]) = make_uint2(0u, 0u);
    }
    int clP[4][4];
#pragma unroll
    for (int Mt = 0; Mt < 4; ++Mt) {
      int4 v = *reinterpret_cast<const int4*>(cls + tile0 + Mt * 16 + quad * 4);
      clP[Mt][0] = v.x; clP[Mt][1] = v.y; clP[Mt][2] = v.z; clP[Mt][3] = v.w;
    }
    __syncthreads();   // B1
    f32x4 a1[2];
#pragma unroll
    for (int m = 0; m < 2; ++m) a1[m] = {b1H, b1H, b1H, b1H};
#pragma unroll 1
    for (int c = 0; c < 2; ++c) {
      // f256 chunk c: wave owns 16 channels (nt = c*8+w), all 4 Mt
      f32x4 f6[4];
#pragma unroll
      for (int Mt = 0; Mt < 4; ++Mt) f6[Mt] = {biH[c], biH[c], biH[c], biH[c]};
      {
        bf16x8 bh, bl;
        bfrag(arena, U_F256 + c * 8 + w, bh, bl);
#pragma unroll
        for (int Mt = 0; Mt < 4; ++Mt) {
          const bf16x8 xah = afragS(Xhi, XSB, Mt, 0), xal = afragS(Xlo, XSB, Mt, 0);
          f6[Mt] = MFMA16(xal, bh, MFMA16(xah, bl, MFMA16(xah, bh, f6[Mt])));
        }
      }
#pragma unroll
      for (int Mt = 0; Mt < 4; ++Mt)
        store_planesF(Fhi, Flo, Mt, n2, relu4(f6[Mt]));
      __syncthreads();   // B2 / B4: chunk staged, X reads done
#pragma unroll
      for (int ks = 0; ks < 4; ++ks) {
        bf16x8 bh, bl;
        bfrag(arena, U_W1_0 + Nt1 * 8 + c * 4 + ks, bh, bl);
#pragma unroll
        for (int m = 0; m < 2; ++m) {
          const bf16x8 ah = afragF(Fhi, mh * 2 + m, ks), al = afragF(Flo, mh * 2 + m, ks);
          a1[m] = MFMA16(al, bh, MFMA16(ah, bl, MFMA16(ah, bh, a1[m])));
        }
      }
      if (c == 1) {      // A64 write into XA: all X reads done (post-B4)
#pragma unroll
        for (int m = 0; m < 2; ++m)
          store_planesS(Ahi, Alo, ASB, mh * 2 + m, n1, relu4(a1[m]));
      }
      __syncthreads();   // B3 / B5: chunk F-reads done (c=1: A staged)
    }
    // w2: wave owns 16 of 128 out, K=64, all Mt
    f32x4 f2[4];
#pragma unroll
    for (int Mt = 0; Mt < 4; ++Mt) f2[Mt] = {b2H, b2H, b2H, b2H};
#pragma unroll
    for (int ks = 0; ks < 2; ++ks) {
      bf16x8 bh, bl;
      bfrag(arena, U_W2_0 + w * 2 + ks, bh, bl);
#pragma unroll
      for (int Mt = 0; Mt < 4; ++Mt) {
        const bf16x8 ah = afragS(Ahi, ASB, Mt, ks), al = afragS(Alo, ASB, Mt, ks);
        f2[Mt] = MFMA16(al, bh, MFMA16(ah, bl, MFMA16(ah, bh, f2[Mt])));
      }
    }
#pragma unroll
    for (int Mt = 0; Mt < 4; ++Mt) {
      f32x4 d = relu4(f2[Mt]);
#pragma unroll
      for (int r = 0; r < 4; ++r)
        atomicMax(&pool_s[n2 * NC + clP[Mt][r]], __float_as_uint(d[r]));
      store_planesF(Fhi, Flo, Mt, n2, d);   // F w1-readers done at B5
    }
    __syncthreads();   // B6: f128 staged
    // w3: wave owns 16 of 128 out, K=128, all Mt
    f32x4 f3a[4];
#pragma unroll
    for (int Mt = 0; Mt < 4; ++Mt) f3a[Mt] = {b3H, b3H, b3H, b3H};
#pragma unroll
    for (int ks = 0; ks < 4; ++ks) {
      bf16x8 bh, bl;
      bfrag(arena, U_W3_0 + w * 4 + ks, bh, bl);
#pragma unroll
      for (int Mt = 0; Mt < 4; ++Mt) {
        const bf16x8 ah = afragF(Fhi, Mt, ks), al = afragF(Flo, Mt, ks);
        f3a[Mt] = MFMA16(al, bh, MFMA16(ah, bl, MFMA16(ah, bh, f3a[Mt])));
      }
    }
    __syncthreads();   // B7: all w3 F-reads done
#pragma unroll
    for (int Mt = 0; Mt < 4; ++Mt)
      store_planesF(Fhi, Flo, Mt, n2, relu4(f3a[Mt]));
    __syncthreads();   // B8: f3 planes staged
    dump_f3(f3g, tile_idx, Fboth, tid);
    // no end barrier: next x-stage writes XA (readers fenced by B5);
    // next F-writes happen post-next-B1; dump LDS-reads complete at next B1.
  }
  for (int i = tid; i < 128 * NC; i += TPB)
    atomicMax(&part0[(size_t)b * 2048 + i], pool_s[i]);
}

// ---- Stages 1,2: f3 -> f64(w1+poolc) -> f128(w2, pooled) -> f3'(w3)
// Double-buffered f3 image; A staged into F cols 0..63 (r15-17-verified).
// LDS 2x32768 + 8192 = 73728 -> 2/CU.
__global__ void __launch_bounds__(TPB, 4) kmid_kern(
    unsigned* __restrict__ f3g, const unsigned* __restrict__ arena,
    const float* __restrict__ poolc_g, unsigned* __restrict__ part_cur,
    const int* __restrict__ clg, const int* __restrict__ clp,
    const float* __restrict__ b2s, const float* __restrict__ b3s,
    int uW1, int uW2, int uW3) {
  __shared__ short Fb[2][2 * PT * FSB];
  __shared__ unsigned pool_s[128 * NC];
  const int tid = threadIdx.x;
  const int lane = tid & 63, w = tid >> 6, l15 = lane & 15, quad = lane >> 4;
  const int b = blockIdx.x >> 6;
  const int Nt1 = w & 3, mh = w >> 2;
  // prologue DMA for tile 0 (no prior readers of Fb[0])
  stage_f3(f3g, blockIdx.x * TILES, Fb[0], w, lane);
  for (int i = tid; i < 128 * NC; i += TPB) pool_s[i] = 0u;
  const float b2H = b2s[w * 16 + l15];
  const float b3H = b3s[w * 16 + l15];
  const int n1 = Nt1 * 16 + l15;
  const int n2 = w * 16 + l15;

  for (int t = 0; t < TILES; ++t) {
    const int tile_idx = blockIdx.x * TILES + t;
    const int tile0 = tile_idx * PT;
    short* Fhi = Fb[t & 1];
    short* Flo = Fhi + FPLANE;
    int clG[2][4], clP[4][4];
#pragma unroll
    for (int m = 0; m < 2; ++m) {
      int4 v = *reinterpret_cast<const int4*>(clg + tile0 + (mh * 2 + m) * 16 + quad * 4);
      clG[m][0] = v.x; clG[m][1] = v.y; clG[m][2] = v.z; clG[m][3] = v.w;
    }
#pragma unroll
    for (int Mt = 0; Mt < 4; ++Mt) {
      int4 v = *reinterpret_cast<const int4*>(clp + tile0 + Mt * 16 + quad * 4);
      clP[Mt][0] = v.x; clP[Mt][1] = v.y; clP[Mt][2] = v.z; clP[Mt][3] = v.w;
    }
    __syncthreads();   // B1: DMA(t) landed; dump(t-1) LDS-reads fenced
    // async prefetch: next tile's f3 into the other buffer (hidden by compute)
    if (t + 1 < TILES)
      stage_f3(f3g, tile_idx + 1, Fb[(t + 1) & 1], w, lane);
    // w1: wave owns 16 of 64 out (Nt1), K=128, Mt = mh*2+m
    f32x4 a1[2];
#pragma unroll
    for (int m = 0; m < 2; ++m)
#pragma unroll
      for (int r = 0; r < 4; ++r)
        a1[m][r] = poolc_g[(size_t)b * 1024 + n1 * 16 + clG[m][r]];
#pragma unroll
    for (int ks = 0; ks < 4; ++ks) {
      bf16x8 bh, bl;
      bfrag(arena, uW1 + Nt1 * 4 + ks, bh, bl);
#pragma unroll
      for (int m = 0; m < 2; ++m) {
        const bf16x8 ah = afragF(Fhi, mh * 2 + m, ks), al = afragF(Flo, mh * 2 + m, ks);
        a1[m] = MFMA16(al, bh, MFMA16(ah, bl, MFMA16(ah, bh, a1[m])));
      }
    }
    __syncthreads();   // B2: all w1 F-reads done
#pragma unroll
    for (int m = 0; m < 2; ++m)
      store_planesF(Fhi, Flo, mh * 2 + m, n1, relu4(a1[m]));   // A -> F cols 0..63
    __syncthreads();   // B3: A staged
    // w2: wave owns 16 of 128 out, K=64 (A in F cols 0..63), all Mt
    f32x4 f2[4];
#pragma unroll
    for (int Mt = 0; Mt < 4; ++Mt) f2[Mt] = {b2H, b2H, b2H, b2H};
#pragma unroll
    for (int ks = 0; ks < 2; ++ks) {
      bf16x8 bh, bl;
      bfrag(arena, uW2 + w * 2 + ks, bh, bl);
#pragma unroll
      for (int Mt = 0; Mt < 4; ++Mt) {
        const bf16x8 ah = afragF(Fhi, Mt, ks), al = afragF(Flo, Mt, ks);
        f2[Mt] = MFMA16(al, bh, MFMA16(ah, bl, MFMA16(ah, bh, f2[Mt])));
      }
    }
    __syncthreads();   // B4: w2 A-reads done
#pragma unroll
    for (int Mt = 0; Mt < 4; ++Mt) {
      f32x4 d = relu4(f2[Mt]);
#pragma unroll
      for (int r = 0; r < 4; ++r)
        atomicMax(&pool_s[n2 * NC + clP[Mt][r]], __float_as_uint(d[r]));
      store_planesF(Fhi, Flo, Mt, n2, d);
    }
    __syncthreads();   // B5: f128 staged
    // w3: wave owns 16 of 128 out, K=128, all Mt
    f32x4 f3a[4];
#pragma unroll
    for (int Mt = 0; Mt < 4; ++Mt) f3a[Mt] = {b3H, b3H, b3H, b3H};
#pragma unroll
    for (int ks = 0; ks < 4; ++ks) {
      bf16x8 bh, bl;
      bfrag(arena, uW3 + w * 4 + ks, bh, bl);
#pragma unroll
      for (int Mt = 0; Mt < 4; ++Mt) {
        const bf16x8 ah = afragF(Fhi, Mt, ks), al = afragF(Flo, Mt, ks);
        f3a[Mt] = MFMA16(al, bh, MFMA16(ah, bl, MFMA16(ah, bh, f3a[Mt])));
      }
    }
    __syncthreads();   // B6: all w3 F-reads done
#pragma unroll
    for (int Mt = 0; Mt < 4; ++Mt)
      store_planesF(Fhi, Flo, Mt, n2, relu4(f3a[Mt]));
    __syncthreads();   // B7: f3' staged
    dump_f3(f3g, tile_idx, Fb[t & 1], tid);
    // no end barrier: dump reads fenced by next B1 before DMA(t+2) reuses buf
  }
  for (int i = tid; i < 128 * NC; i += TPB)
    atomicMax(&part_cur[(size_t)b * 2048 + i], pool_s[i]);
}

// ---- Head: f3_2 -> o1(wo1+poolco) -> o2(wo2) -> global max
// Double-buffered f3 image. LDS 2x32768 = 65536 -> 2/CU. 3 barriers/tile.
__global__ void __launch_bounds__(TPB, 4) k3_kern(
    const unsigned* __restrict__ f3g, const unsigned* __restrict__ arena,
    const float* __restrict__ poolco_g, const int* __restrict__ clg,
    const float* __restrict__ bo2, unsigned* __restrict__ out) {
  __shared__ short Fb[2][2 * PT * FSB];
  const int tid = threadIdx.x;
  const int lane = tid & 63, w = tid >> 6, l15 = lane & 15, quad = lane >> 4;
  const int b = blockIdx.x >> 6;
  const float bo2H = bo2[w * 16 + l15];
  const int n2 = w * 16 + l15;
  float omax = 0.f;
  stage_f3(f3g, blockIdx.x * TILES, Fb[0], w, lane);   // prologue DMA

  for (int t = 0; t < TILES; ++t) {
    const int tile_idx = blockIdx.x * TILES + t;
    const int tile0 = tile_idx * PT;
    short* Fhi = Fb[t & 1];
    short* Flo = Fhi + FPLANE;
    int clA[4][4];
#pragma unroll
    for (int Mt = 0; Mt < 4; ++Mt) {
      int4 v = *reinterpret_cast<const int4*>(clg + tile0 + Mt * 16 + quad * 4);
      clA[Mt][0] = v.x; clA[Mt][1] = v.y; clA[Mt][2] = v.z; clA[Mt][3] = v.w;
    }
    __syncthreads();   // B1: DMA(t) landed; prev o2-reads of other buf fenced
    if (t + 1 < TILES)
      stage_f3(f3g, tile_idx + 1, Fb[(t + 1) & 1], w, lane);
    f32x4 o1a[4];
#pragma unroll
    for (int Mt = 0; Mt < 4; ++Mt)
#pragma unroll
      for (int r = 0; r < 4; ++r)
        o1a[Mt][r] = poolco_g[(size_t)b * 2048 + n2 * 16 + clA[Mt][r]];
#pragma unroll
    for (int ks = 0; ks < 4; ++ks) {
      bf16x8 bh, bl;
      bfrag(arena, U_O1 + w * 4 + ks, bh, bl);
#pragma unroll
      for (int Mt = 0; Mt < 4; ++Mt) {
        const bf16x8 ah = afragF(Fhi, Mt, ks), al = afragF(Flo, Mt, ks);
        o1a[Mt] = MFMA16(al, bh, MFMA16(ah, bl, MFMA16(ah, bh, o1a[Mt])));
      }
    }
    __syncthreads();   // B2: o1 F-reads done
#pragma unroll
    for (int Mt = 0; Mt < 4; ++Mt)
      store_planesF(Fhi, Flo, Mt, n2, relu4(o1a[Mt]));
    __syncthreads();   // B3: o1 staged
    f32x4 o2a[4];
#pragma unroll
    for (int Mt = 0; Mt < 4; ++Mt) o2a[Mt] = {bo2H, bo2H, bo2H, bo2H};
#pragma unroll
    for (int ks = 0; ks < 4; ++ks) {
      bf16x8 bh, bl;
      bfrag(arena, U_O2 + w * 4 + ks, bh, bl);
#pragma unroll
      for (int Mt = 0; Mt < 4; ++Mt) {
        const bf16x8 ah = afragF(Fhi, Mt, ks), al = afragF(Flo, Mt, ks);
        o2a[Mt] = MFMA16(al, bh, MFMA16(ah, bl, MFMA16(ah, bh, o2a[Mt])));
      }
    }
#pragma unroll
    for (int Mt = 0; Mt < 4; ++Mt) {
      f32x4 d = relu4(o2a[Mt]);
      omax = fmaxf(omax, fmaxf(fmaxf(d[0], d[1]), fmaxf(d[2], d[3])));
    }
    // no end barrier: o2 reads of this buf are fenced by next-tile B1 before
    // DMA(t+2) can overwrite it.
  }
  omax = fmaxf(omax, __shfl_xor(omax, 16));
  omax = fmaxf(omax, __shfl_xor(omax, 32));
  if (lane < 16)
    atomicMax(&out[b * 128 + w * 16 + lane], __float_as_uint(omax));
}

extern "C" void kernel_launch(void* const* d_in, const int* in_sizes, int n_in,
                              void* d_out, int out_size, void* d_ws, size_t ws_size,
                              hipStream_t stream) {
  const float* x    = (const float*)d_in[0];
  const int*   cls  = (const int*)d_in[1];
  const float* w_in = (const float*)d_in[2];
  const float* b_in = (const float*)d_in[3];
  const float* w1   = (const float*)d_in[4];
  const float* b1   = (const float*)d_in[5];
  const float* w2   = (const float*)d_in[6];
  const float* b2   = (const float*)d_in[7];
  const float* w3   = (const float*)d_in[8];
  const float* b3   = (const float*)d_in[9];
  const float* wo1  = (const float*)d_in[10];
  const float* bo1  = (const float*)d_in[11];
  const float* wo2  = (const float*)d_in[12];
  const float* bo2  = (const float*)d_in[13];

  char* ws = (char*)d_ws;
  unsigned* f3g = (unsigned*)ws;                            // 64 MB LDS image
  unsigned* part0 = (unsigned*)(ws + ((size_t)64 << 20));   // 3 x 8 KB
  unsigned* part1 = part0 + 8 * 2048;
  unsigned* part2 = part1 + 8 * 2048;
  float* poolc1 = (float*)(part2 + 8 * 2048);               // 8*1024
  float* poolc2 = poolc1 + 8 * 1024;
  float* poolco = poolc2 + 8 * 1024;                        // 8*2048
  unsigned* arena = (unsigned*)(poolco + 8 * 2048);         // 288*512 dwords

  hipMemsetAsync(d_out, 0, 1024 * sizeof(float), stream);
  hipMemsetAsync(part0, 0, 3 * 8 * 2048 * sizeof(unsigned), stream);

  prep_frags<<<N_UNITS, 64, 0, stream>>>(w_in, w1, w2, w3, wo1, wo2, arena);
  k0_kern<<<NBLK, TPB, 0, stream>>>(x, cls, b_in, b1, b2, b3, arena, f3g, part0);
  pool_reduce_kern<64><<<8, 1024, 0, stream>>>(part0, w1 + (size_t)64 * 256, b1 + 64, poolc1);
  kmid_kern<<<NBLK, TPB, 0, stream>>>(f3g, arena, poolc1, part1, cls, cls + NPTS,
                                      b2 + 128, b3 + 128, U_W1_1, U_W2_1, U_W3_1);
  pool_reduce_kern<64><<<8, 1024, 0, stream>>>(part1, w1 + (size_t)2 * 64 * 256, b1 + 128, poolc2);
  kmid_kern<<<NBLK, TPB, 0, stream>>>(f3g, arena, poolc2, part2, cls + NPTS, cls + 2 * NPTS,
                                      b2 + 256, b3 + 256, U_W1_2, U_W2_2, U_W3_2);
  pool_reduce_kern<128><<<8, 1024, 0, stream>>>(part2, wo1, bo1, poolco);
  k3_kern<<<NBLK, TPB, 0, stream>>>(f3g, arena, poolco, cls + 2 * NPTS, bo2, (unsigned*)d_out);
}

// Round 12
// 355.605 us; speedup vs baseline: 1.1644x; 1.1644x over previous
//
#include <hip/hip_runtime.h>

// LapCluster MI355X — round 20 resubmit (r21): container-broker failure on
// the previous attempt (no signal). Kernel unchanged.
// r19 post-mortem: dbuf+prefetch REGRESSED (388->414; kmid 84->92.5).
// Root cause: compiler drains vmcnt(0) at EVERY s_barrier -> a DMA issued
// after B1 is forced to land at B2, hiding only under the short w1 phase,
// while A-in-F added a 7th barrier. Lesson: cross-barrier DMA pipelining
// cannot work at HIP source in a multi-barrier tile; r18's issue-at-loop-top/
// drain-at-B1 is already the optimal placement. REVERTED to r18 verbatim.
// One low-risk addition (same remove-work-from-serial-chain family):
// poolc/poolco gathers (8-16 scattered 4B global loads/thread/tile) ->
// LDS tables staged once per block with coalesced loads. kmid pltab 4KB
// (LDS 59392->63488, still 2/CU), k3 ptab 8KB (32768->40960). First use
// fenced by tile-0 B1. Everything else byte-identical to r18.
// Predict: kmid ~80->76-80us, FETCH 123->~118MB, total 388->375-385.

typedef __attribute__((ext_vector_type(8))) short bf16x8;
typedef __attribute__((ext_vector_type(4))) float f32x4;
typedef __attribute__((ext_vector_type(4))) unsigned u32x4;
typedef __attribute__((ext_vector_type(4))) float f32x4v;

#define MFMA16(a, b, c) __builtin_amdgcn_mfma_f32_16x16x32_bf16((a), (b), (c), 0, 0, 0)

#define TPB 512
#define PT 64
#define NPTS 131072
#define NC 16
#define TILES 4
#define NBLK 512         // 64 blocks/batch

#define FSB 128          // F plane stride (shorts) — bank-swizzled, image-linear
#define ASB 72           // A64 plane stride (padded, unswizzled)
#define XSB 40           // x staging stride (padded, unswizzled)
#define TILE_BYTES (2 * PT * FSB * 2)   // 32768 B per f3 tile image
#define FPLANE (PT * FSB)

// frag arena units (1 unit = 64 lanes * 8 dwords: [0..3]=hi frag, [4..7]=lo)
#define U_F256 0
#define U_W1_0 16
#define U_W2_0 48
#define U_W3_0 64
#define U_W1_1 96
#define U_W2_1 112
#define U_W3_1 128
#define U_W1_2 160
#define U_W2_2 176
#define U_W3_2 192
#define U_O1   224
#define U_O2   256
#define N_UNITS 288

// XOR bank swizzle within a row (F planes only): bijective per row, keeps
// 16B alignment of 8-short groups. Verified r16-r19.
__device__ __forceinline__ int swz(int row, int col) {
  return col ^ ((row & 7) << 3);
}

__device__ __forceinline__ f32x4 relu4(f32x4 a) {
#pragma unroll
  for (int r = 0; r < 4; ++r) a[r] = fmaxf(a[r], 0.f);
  return a;
}

// swizzled fragment read from an F plane (FSB)
__device__ __forceinline__ bf16x8 afragF(const short* plane, int mt, int ks) {
  const int lane = threadIdx.x & 63;
  const int row = mt * 16 + (lane & 15);
  const int col = ks * 32 + (lane >> 4) * 8;
  return *reinterpret_cast<const bf16x8*>(plane + row * FSB + swz(row, col));
}

// plain strided fragment read (X/A planes)
__device__ __forceinline__ bf16x8 afragS(const short* plane, int stride, int mt, int ks) {
  const int lane = threadIdx.x & 63;
  return *reinterpret_cast<const bf16x8*>(
      plane + (mt * 16 + (lane & 15)) * stride + ks * 32 + (lane >> 4) * 8);
}

__device__ __forceinline__ void bfrag(const unsigned* __restrict__ arena, int unit,
                                      bf16x8& h, bf16x8& l) {
  const bf16x8* p = reinterpret_cast<const bf16x8*>(
      arena + ((size_t)unit * 64 + (threadIdx.x & 63)) * 8);
  h = p[0];
  l = p[1];
}

// write relu'd D (4 regs = pts mt*16 + quad*4 + r) into swizzled F planes
__device__ __forceinline__ void store_planesF(short* hp, short* lp,
                                              int mt, int n, f32x4 d) {
  const int m0 = mt * 16 + ((threadIdx.x & 63) >> 4) * 4;
#pragma unroll
  for (int r = 0; r < 4; ++r) {
    const int row = m0 + r;
    const int c = swz(row, n);
    unsigned uv = __float_as_uint(d[r]);
    unsigned hm = uv & 0xFFFF0000u;
    float lo = d[r] - __uint_as_float(hm);
    hp[row * FSB + c] = (short)(hm >> 16);
    lp[row * FSB + c] = (short)(__float_as_uint(lo) >> 16);
  }
}

// plain strided store (A planes)
__device__ __forceinline__ void store_planesS(short* hp, short* lp, int stride,
                                              int mt, int n, f32x4 d) {
  const int m0 = mt * 16 + ((threadIdx.x & 63) >> 4) * 4;
#pragma unroll
  for (int r = 0; r < 4; ++r) {
    unsigned uv = __float_as_uint(d[r]);
    unsigned hm = uv & 0xFFFF0000u;
    float lo = d[r] - __uint_as_float(hm);
    hp[(m0 + r) * stride + n] = (short)(hm >> 16);
    lp[(m0 + r) * stride + n] = (short)(__float_as_uint(lo) >> 16);
  }
}

// ---- async global->LDS 16B (linear identity copy)
__device__ __forceinline__ void gl_lds16(const char* g, const char* l) {
  typedef __attribute__((address_space(1))) const unsigned as1_u32;
  typedef __attribute__((address_space(3))) unsigned as3_u32;
  as1_u32* gp = reinterpret_cast<as1_u32*>((unsigned long long)g);
  as3_u32* lp = reinterpret_cast<as3_u32*>((unsigned)(unsigned long long)l);
  __builtin_amdgcn_global_load_lds(gp, lp, 16, 0, 0);
}

// stage-in: f3g tile image -> Fboth, 32 x 1KB wave-segments via DMA
__device__ __forceinline__ void stage_f3(const unsigned* __restrict__ f3g,
                                         int tile_idx, short* Fboth,
                                         int w, int lane) {
  const char* g = reinterpret_cast<const char*>(f3g) + (size_t)tile_idx * TILE_BYTES;
  const char* l = reinterpret_cast<const char*>(Fboth);
#pragma unroll
  for (int i = 0; i < 4; ++i) {
    const int seg = i * 8 + w;
    gl_lds16(g + seg * 1024 + lane * 16, l + seg * 1024);
  }
}

// dump-out: Fboth -> f3g tile image, linear coalesced uint4 copy
__device__ __forceinline__ void dump_f3(unsigned* __restrict__ f3g, int tile_idx,
                                        const short* Fboth, int tid) {
  u32x4* dst = reinterpret_cast<u32x4*>(
      reinterpret_cast<char*>(f3g) + (size_t)tile_idx * TILE_BYTES);
  const u32x4* src = reinterpret_cast<const u32x4*>(Fboth);
#pragma unroll
  for (int i = 0; i < 4; ++i)
    dst[i * TPB + tid] = src[i * TPB + tid];
}

// ---- prep: split weights into fragment-ordered hi/lo bf16 arenas (unchanged)
__global__ void __launch_bounds__(64) prep_frags(
    const float* __restrict__ w_in, const float* __restrict__ w1,
    const float* __restrict__ w2, const float* __restrict__ w3,
    const float* __restrict__ wo1, const float* __restrict__ wo2,
    unsigned* __restrict__ arena) {
  const int unit = blockIdx.x;
  const int lane = threadIdx.x;
  const float* W; int KS, Klog, rs, u;
  if (unit < U_W1_0)      { W = w_in;                   u = unit - U_F256; KS = 1; Klog = 28;  rs = 28;  }
  else if (unit < U_W2_0) { W = w1;                     u = unit - U_W1_0; KS = 8; Klog = 256; rs = 256; }
  else if (unit < U_W3_0) { W = w2;                     u = unit - U_W2_0; KS = 2; Klog = 64;  rs = 64;  }
  else if (unit < U_W1_1) { W = w3;                     u = unit - U_W3_0; KS = 4; Klog = 128; rs = 128; }
  else if (unit < U_W2_1) { W = w1 + 64 * 256;          u = unit - U_W1_1; KS = 4; Klog = 128; rs = 256; }
  else if (unit < U_W3_1) { W = w2 + 128 * 64;          u = unit - U_W2_1; KS = 2; Klog = 64;  rs = 64;  }
  else if (unit < U_W1_2) { W = w3 + 128 * 128;         u = unit - U_W3_1; KS = 4; Klog = 128; rs = 128; }
  else if (unit < U_W2_2) { W = w1 + 2 * 64 * 256;      u = unit - U_W1_2; KS = 4; Klog = 128; rs = 256; }
  else if (unit < U_W3_2) { W = w2 + 2 * 128 * 64;      u = unit - U_W2_2; KS = 2; Klog = 64;  rs = 64;  }
  else if (unit < U_O1)   { W = w3 + 2 * 128 * 128;     u = unit - U_W3_2; KS = 4; Klog = 128; rs = 128; }
  else if (unit < U_O2)   { W = wo1;                    u = unit - U_O1;   KS = 4; Klog = 128; rs = 256; }
  else                    { W = wo2;                    u = unit - U_O2;   KS = 4; Klog = 128; rs = 128; }
  const int nt = u / KS, ks = u % KS;
  const int n = nt * 16 + (lane & 15);
  const int k0 = ks * 32 + (lane >> 4) * 8;
  unsigned hiD[4], loD[4];
#pragma unroll
  for (int d = 0; d < 4; ++d) {
    unsigned hu[2], lu[2];
#pragma unroll
    for (int e = 0; e < 2; ++e) {
      const int k = k0 + d * 2 + e;
      float v = (k < Klog) ? W[(size_t)n * rs + k] : 0.f;
      unsigned uv = __float_as_uint(v);
      unsigned hm = uv & 0xFFFF0000u;
      float lo = v - __uint_as_float(hm);
      hu[e] = hm >> 16;
      lu[e] = __float_as_uint(lo) >> 16;
    }
    hiD[d] = hu[0] | (hu[1] << 16);
    loD[d] = lu[0] | (lu[1] << 16);
  }
  unsigned* dst = arena + ((size_t)unit * 64 + lane) * 8;
  *reinterpret_cast<uint4*>(dst)     = make_uint4(hiD[0], hiD[1], hiD[2], hiD[3]);
  *reinterpret_cast<uint4*>(dst + 4) = make_uint4(loD[0], loD[1], loD[2], loD[3]);
}

// ---- per-batch poolc table (fp32) — unchanged
template<int O>
__global__ void __launch_bounds__(1024) pool_reduce_kern(
    const unsigned* __restrict__ part, const float* __restrict__ W,
    const float* __restrict__ bias, float* __restrict__ poolc_g) {
  __shared__ float pfL[2048];
  __shared__ float Wl[O * 129];
  const int tid = threadIdx.x;
  const int b = blockIdx.x;
  for (int i = tid; i < 2048; i += 1024) pfL[i] = __uint_as_float(part[b * 2048 + i]);
  for (int i = tid; i < O * 128; i += 1024) {
    const int o = i >> 7, k = i & 127;
    Wl[o * 129 + k] = W[o * 256 + 128 + k];
  }
  __syncthreads();
  constexpr int SH = (O == 64) ? 6 : 7;
  for (int e = tid; e < O * 16; e += 1024) {
    const int o = e & (O - 1);
    const int cl = e >> SH;
    float s = bias[o];
    const float* wr = &Wl[o * 129];
    const float* pr = &pfL[cl];
#pragma unroll 4
    for (int k = 0; k < 128; ++k) s = fmaf(wr[k], pr[k * 16], s);
    poolc_g[(size_t)b * (O * 16) + o * 16 + cl] = s;
  }
}

// ---- Stage 0: unchanged from r18
__global__ void __launch_bounds__(TPB, 4) k0_kern(
    const float* __restrict__ x, const int* __restrict__ cls,
    const float* __restrict__ b_in, const float* __restrict__ b1,
    const float* __restrict__ b2, const float* __restrict__ b3,
    const unsigned* __restrict__ arena,
    unsigned* __restrict__ f3g, unsigned* __restrict__ part0) {
  __shared__ short Fboth[2 * PT * FSB];            // [hi 16KB][lo 16KB] image
  __shared__ short XA[PT * ASB * 2];               // x planes alias A64 planes
  __shared__ unsigned pool_s[128 * NC];
  short* Fhi = Fboth;  short* Flo = Fboth + FPLANE;
  short* Xhi = XA;  short* Xlo = XA + PT * XSB;
  short* Ahi = XA;  short* Alo = XA + PT * ASB;
  const int tid = threadIdx.x;
  const int lane = tid & 63, w = tid >> 6, l15 = lane & 15, quad = lane >> 4;
  const int b = blockIdx.x >> 6;
  const int Nt1 = w & 3, mh = w >> 2;
  for (int i = tid; i < 128 * NC; i += TPB) pool_s[i] = 0u;

  float biH[2];
#pragma unroll
  for (int c = 0; c < 2; ++c) biH[c] = b_in[c * 128 + w * 16 + l15];
  const float b1H = b1[Nt1 * 16 + l15];
  const float b2H = b2[w * 16 + l15];
  const float b3H = b3[w * 16 + l15];
  const int n1 = Nt1 * 16 + l15;
  const int n2 = w * 16 + l15;
  const int xpt = (tid < 448) ? tid / 7 : 0;
  const int xc4 = (tid < 448) ? (tid - xpt * 7) * 4 : 0;

  for (int t = 0; t < TILES; ++t) {
    const int tile_idx = blockIdx.x * TILES + t;
    const int tile0 = tile_idx * PT;
    if (tid < 448) {   // stage x hi/lo
      const f32x4v v = __builtin_nontemporal_load(
          reinterpret_cast<const f32x4v*>(x + (size_t)(tile0 + xpt) * 28 + xc4));
      unsigned h0 = __float_as_uint(v.x) & 0xFFFF0000u, h1 = __float_as_uint(v.y) & 0xFFFF0000u;
      unsigned h2 = __float_as_uint(v.z) & 0xFFFF0000u, h3 = __float_as_uint(v.w) & 0xFFFF0000u;
      uint2 hd, ld;
      hd.x = (h0 >> 16) | h1;
      hd.y = (h2 >> 16) | h3;
      ld.x = (__float_as_uint(v.x - __uint_as_float(h0)) >> 16) |
             (__float_as_uint(v.y - __uint_as_float(h1)) & 0xFFFF0000u);
      ld.y = (__float_as_uint(v.z - __uint_as_float(h2)) >> 16) |
             (__float_as_uint(v.w - __uint_as_float(h3)) & 0xFFFF0000u);
      *reinterpret_cast<uint2*>(&Xhi[xpt * XSB + xc4]) = hd;
      *reinterpret_cast<uint2*>(&Xlo[xpt * XSB + xc4]) = ld;
    } else {           // zero k pads 28..31 (region aliased by A64 last tile)
      const int p = tid - 448;
      *reinterpret_cast<uint2*>(&Xhi[p * XSB + 28]) = make_uint2(0u, 0u);
      *reinterpret_cast<uint2*>(&Xlo[p * XSB + 28]) = make_uint2(0u, 0u);
    }
    int clP[4][4];
#pragma unroll
    for (int Mt = 0; Mt < 4; ++Mt) {
      int4 v = *reinterpret_cast<const int4*>(cls + tile0 + Mt * 16 + quad * 4);
      clP[Mt][0] = v.x; clP[Mt][1] = v.y; clP[Mt][2] = v.z; clP[Mt][3] = v.w;
    }
    __syncthreads();   // B1
    f32x4 a1[2];
#pragma unroll
    for (int m = 0; m < 2; ++m) a1[m] = {b1H, b1H, b1H, b1H};
#pragma unroll 1
    for (int c = 0; c < 2; ++c) {
      // f256 chunk c: wave owns 16 channels (nt = c*8+w), all 4 Mt
      f32x4 f6[4];
#pragma unroll
      for (int Mt = 0; Mt < 4; ++Mt) f6[Mt] = {biH[c], biH[c], biH[c], biH[c]};
      {
        bf16x8 bh, bl;
        bfrag(arena, U_F256 + c * 8 + w, bh, bl);
#pragma unroll
        for (int Mt = 0; Mt < 4; ++Mt) {
          const bf16x8 xah = afragS(Xhi, XSB, Mt, 0), xal = afragS(Xlo, XSB, Mt, 0);
          f6[Mt] = MFMA16(xal, bh, MFMA16(xah, bl, MFMA16(xah, bh, f6[Mt])));
        }
      }
#pragma unroll
      for (int Mt = 0; Mt < 4; ++Mt)
        store_planesF(Fhi, Flo, Mt, n2, relu4(f6[Mt]));
      __syncthreads();   // B2 / B4: chunk staged, X reads done
#pragma unroll
      for (int ks = 0; ks < 4; ++ks) {
        bf16x8 bh, bl;
        bfrag(arena, U_W1_0 + Nt1 * 8 + c * 4 + ks, bh, bl);
#pragma unroll
        for (int m = 0; m < 2; ++m) {
          const bf16x8 ah = afragF(Fhi, mh * 2 + m, ks), al = afragF(Flo, mh * 2 + m, ks);
          a1[m] = MFMA16(al, bh, MFMA16(ah, bl, MFMA16(ah, bh, a1[m])));
        }
      }
      if (c == 1) {      // A64 write into XA: all X reads done (post-B4)
#pragma unroll
        for (int m = 0; m < 2; ++m)
          store_planesS(Ahi, Alo, ASB, mh * 2 + m, n1, relu4(a1[m]));
      }
      __syncthreads();   // B3 / B5: chunk F-reads done (c=1: A staged)
    }
    // w2: wave owns 16 of 128 out, K=64, all Mt
    f32x4 f2[4];
#pragma unroll
    for (int Mt = 0; Mt < 4; ++Mt) f2[Mt] = {b2H, b2H, b2H, b2H};
#pragma unroll
    for (int ks = 0; ks < 2; ++ks) {
      bf16x8 bh, bl;
      bfrag(arena, U_W2_0 + w * 2 + ks, bh, bl);
#pragma unroll
      for (int Mt = 0; Mt < 4; ++Mt) {
        const bf16x8 ah = afragS(Ahi, ASB, Mt, ks), al = afragS(Alo, ASB, Mt, ks);
        f2[Mt] = MFMA16(al, bh, MFMA16(ah, bl, MFMA16(ah, bh, f2[Mt])));
      }
    }
#pragma unroll
    for (int Mt = 0; Mt < 4; ++Mt) {
      f32x4 d = relu4(f2[Mt]);
#pragma unroll
      for (int r = 0; r < 4; ++r)
        atomicMax(&pool_s[n2 * NC + clP[Mt][r]], __float_as_uint(d[r]));
      store_planesF(Fhi, Flo, Mt, n2, d);   // F w1-readers done at B5
    }
    __syncthreads();   // B6: f128 staged
    // w3: wave owns 16 of 128 out, K=128, all Mt
    f32x4 f3a[4];
#pragma unroll
    for (int Mt = 0; Mt < 4; ++Mt) f3a[Mt] = {b3H, b3H, b3H, b3H};
#pragma unroll
    for (int ks = 0; ks < 4; ++ks) {
      bf16x8 bh, bl;
      bfrag(arena, U_W3_0 + w * 4 + ks, bh, bl);
#pragma unroll
      for (int Mt = 0; Mt < 4; ++Mt) {
        const bf16x8 ah = afragF(Fhi, Mt, ks), al = afragF(Flo, Mt, ks);
        f3a[Mt] = MFMA16(al, bh, MFMA16(ah, bl, MFMA16(ah, bh, f3a[Mt])));
      }
    }
    __syncthreads();   // B7: all w3 F-reads done
#pragma unroll
    for (int Mt = 0; Mt < 4; ++Mt)
      store_planesF(Fhi, Flo, Mt, n2, relu4(f3a[Mt]));
    __syncthreads();   // B8: f3 planes staged
    dump_f3(f3g, tile_idx, Fboth, tid);
    // no end barrier: next x-stage writes XA (readers fenced by B5);
    // next F-writes happen post-next-B1; dump LDS-reads complete at next B1.
  }
  for (int i = tid; i < 128 * NC; i += TPB)
    atomicMax(&part0[(size_t)b * 2048 + i], pool_s[i]);
}

// ---- Stages 1,2: f3 -> f64(w1+poolc) -> f128(w2, pooled) -> f3'(w3)
// r18 structure + poolc staged into LDS (pltab 4KB, coalesced).
__global__ void __launch_bounds__(TPB, 4) kmid_kern(
    unsigned* __restrict__ f3g, const unsigned* __restrict__ arena,
    const float* __restrict__ poolc_g, unsigned* __restrict__ part_cur,
    const int* __restrict__ clg, const int* __restrict__ clp,
    const float* __restrict__ b2s, const float* __restrict__ b3s,
    int uW1, int uW2, int uW3) {
  __shared__ short Fboth[2 * PT * FSB];
  __shared__ short Ahi[PT * ASB], Alo[PT * ASB];
  __shared__ unsigned pool_s[128 * NC];
  __shared__ float pltab[1024];            // poolc table, LDS-local gathers
  short* Fhi = Fboth;  short* Flo = Fboth + FPLANE;
  const int tid = threadIdx.x;
  const int lane = tid & 63, w = tid >> 6, l15 = lane & 15, quad = lane >> 4;
  const int b = blockIdx.x >> 6;
  const int Nt1 = w & 3, mh = w >> 2;
  for (int i = tid; i < 128 * NC; i += TPB) pool_s[i] = 0u;
  for (int i = tid; i < 1024; i += TPB)    // coalesced stage; fenced by t0's B1
    pltab[i] = poolc_g[(size_t)b * 1024 + i];
  const float b2H = b2s[w * 16 + l15];
  const float b3H = b3s[w * 16 + l15];
  const int n1 = Nt1 * 16 + l15;
  const int n2 = w * 16 + l15;

  for (int t = 0; t < TILES; ++t) {
    const int tile_idx = blockIdx.x * TILES + t;
    const int tile0 = tile_idx * PT;
    stage_f3(f3g, tile_idx, Fboth, w, lane);   // DMA: global image -> LDS
    int clG[2][4], clP[4][4];
#pragma unroll
    for (int m = 0; m < 2; ++m) {
      int4 v = *reinterpret_cast<const int4*>(clg + tile0 + (mh * 2 + m) * 16 + quad * 4);
      clG[m][0] = v.x; clG[m][1] = v.y; clG[m][2] = v.z; clG[m][3] = v.w;
    }
#pragma unroll
    for (int Mt = 0; Mt < 4; ++Mt) {
      int4 v = *reinterpret_cast<const int4*>(clp + tile0 + Mt * 16 + quad * 4);
      clP[Mt][0] = v.x; clP[Mt][1] = v.y; clP[Mt][2] = v.z; clP[Mt][3] = v.w;
    }
    __syncthreads();   // B1: staged (vmcnt drained -> DMA landed; pltab ready)
    // w1: wave owns 16 of 64 out (Nt1), K=128, Mt = mh*2+m
    f32x4 a1[2];
#pragma unroll
    for (int m = 0; m < 2; ++m)
#pragma unroll
      for (int r = 0; r < 4; ++r)
        a1[m][r] = pltab[n1 * 16 + clG[m][r]];
#pragma unroll
    for (int ks = 0; ks < 4; ++ks) {
      bf16x8 bh, bl;
      bfrag(arena, uW1 + Nt1 * 4 + ks, bh, bl);
#pragma unroll
      for (int m = 0; m < 2; ++m) {
        const bf16x8 ah = afragF(Fhi, mh * 2 + m, ks), al = afragF(Flo, mh * 2 + m, ks);
        a1[m] = MFMA16(al, bh, MFMA16(ah, bl, MFMA16(ah, bh, a1[m])));
      }
    }
#pragma unroll
    for (int m = 0; m < 2; ++m)
      store_planesS(Ahi, Alo, ASB, mh * 2 + m, n1, relu4(a1[m]));
    __syncthreads();   // B2: A64 staged
    // w2: wave owns 16 of 128 out, K=64, all Mt
    f32x4 f2[4];
#pragma unroll
    for (int Mt = 0; Mt < 4; ++Mt) f2[Mt] = {b2H, b2H, b2H, b2H};
#pragma unroll
    for (int ks = 0; ks < 2; ++ks) {
      bf16x8 bh, bl;
      bfrag(arena, uW2 + w * 2 + ks, bh, bl);
#pragma unroll
      for (int Mt = 0; Mt < 4; ++Mt) {
        const bf16x8 ah = afragS(Ahi, ASB, Mt, ks), al = afragS(Alo, ASB, Mt, ks);
        f2[Mt] = MFMA16(al, bh, MFMA16(ah, bl, MFMA16(ah, bh, f2[Mt])));
      }
    }
#pragma unroll
    for (int Mt = 0; Mt < 4; ++Mt) {
      f32x4 d = relu4(f2[Mt]);
#pragma unroll
      for (int r = 0; r < 4; ++r)
        atomicMax(&pool_s[n2 * NC + clP[Mt][r]], __float_as_uint(d[r]));
      store_planesF(Fhi, Flo, Mt, n2, d);   // F w1-readers done at B2
    }
    __syncthreads();   // B3: f128 staged
    // w3: wave owns 16 of 128 out, K=128, all Mt
    f32x4 f3a[4];
#pragma unroll
    for (int Mt = 0; Mt < 4; ++Mt) f3a[Mt] = {b3H, b3H, b3H, b3H};
#pragma unroll
    for (int ks = 0; ks < 4; ++ks) {
      bf16x8 bh, bl;
      bfrag(arena, uW3 + w * 4 + ks, bh, bl);
#pragma unroll
      for (int Mt = 0; Mt < 4; ++Mt) {
        const bf16x8 ah = afragF(Fhi, Mt, ks), al = afragF(Flo, Mt, ks);
        f3a[Mt] = MFMA16(al, bh, MFMA16(ah, bl, MFMA16(ah, bh, f3a[Mt])));
      }
    }
    __syncthreads();   // B4: all w3 F-reads done
#pragma unroll
    for (int Mt = 0; Mt < 4; ++Mt)
      store_planesF(Fhi, Flo, Mt, n2, relu4(f3a[Mt]));
    __syncthreads();   // B5: f3 planes staged
    dump_f3(f3g, tile_idx, Fboth, tid);
    __syncthreads();   // B6: dump reads done before next stage-in overwrite
  }
  for (int i = tid; i < 128 * NC; i += TPB)
    atomicMax(&part_cur[(size_t)b * 2048 + i], pool_s[i]);
}

// ---- Head: f3_2 -> o1(wo1+poolco) -> o2(wo2) -> global max
// r18 structure + poolco staged into LDS (ptab 8KB, coalesced).
__global__ void __launch_bounds__(TPB, 4) k3_kern(
    const unsigned* __restrict__ f3g, const unsigned* __restrict__ arena,
    const float* __restrict__ poolco_g, const int* __restrict__ clg,
    const float* __restrict__ bo2, unsigned* __restrict__ out) {
  __shared__ short Fboth[2 * PT * FSB];
  __shared__ float ptab[2048];             // poolco table, LDS-local gathers
  short* Fhi = Fboth;  short* Flo = Fboth + FPLANE;
  const int tid = threadIdx.x;
  const int lane = tid & 63, w = tid >> 6, l15 = lane & 15, quad = lane >> 4;
  const int b = blockIdx.x >> 6;
  const float bo2H = bo2[w * 16 + l15];
  const int n2 = w * 16 + l15;
  float omax = 0.f;
  for (int i = tid; i < 2048; i += TPB)    // coalesced stage; fenced by t0's B1
    ptab[i] = poolco_g[(size_t)b * 2048 + i];

  for (int t = 0; t < TILES; ++t) {
    const int tile_idx = blockIdx.x * TILES + t;
    const int tile0 = tile_idx * PT;
    stage_f3(f3g, tile_idx, Fboth, w, lane);
    int clA[4][4];
#pragma unroll
    for (int Mt = 0; Mt < 4; ++Mt) {
      int4 v = *reinterpret_cast<const int4*>(clg + tile0 + Mt * 16 + quad * 4);
      clA[Mt][0] = v.x; clA[Mt][1] = v.y; clA[Mt][2] = v.z; clA[Mt][3] = v.w;
    }
    __syncthreads();   // B1 (DMA landed; ptab ready)
    f32x4 o1a[4];
#pragma unroll
    for (int Mt = 0; Mt < 4; ++Mt)
#pragma unroll
      for (int r = 0; r < 4; ++r)
        o1a[Mt][r] = ptab[n2 * 16 + clA[Mt][r]];
#pragma unroll
    for (int ks = 0; ks < 4; ++ks) {
      bf16x8 bh, bl;
      bfrag(arena, U_O1 + w * 4 + ks, bh, bl);
#pragma unroll
      for (int Mt = 0; Mt < 4; ++Mt) {
        const bf16x8 ah = afragF(Fhi, Mt, ks), al = afragF(Flo, Mt, ks);
        o1a[Mt] = MFMA16(al, bh, MFMA16(ah, bl, MFMA16(ah, bh, o1a[Mt])));
      }
    }
    __syncthreads();   // B2: o1 F-reads done
#pragma unroll
    for (int Mt = 0; Mt < 4; ++Mt)
      store_planesF(Fhi, Flo, Mt, n2, relu4(o1a[Mt]));
    __syncthreads();   // B3: o1 staged
    f32x4 o2a[4];
#pragma unroll
    for (int Mt = 0; Mt < 4; ++Mt) o2a[Mt] = {bo2H, bo2H, bo2H, bo2H};
#pragma unroll
    for (int ks = 0; ks < 4; ++ks) {
      bf16x8 bh, bl;
      bfrag(arena, U_O2 + w * 4 + ks, bh, bl);
#pragma unroll
      for (int Mt = 0; Mt < 4; ++Mt) {
        const bf16x8 ah = afragF(Fhi, Mt, ks), al = afragF(Flo, Mt, ks);
        o2a[Mt] = MFMA16(al, bh, MFMA16(ah, bl, MFMA16(ah, bh, o2a[Mt])));
      }
    }
#pragma unroll
    for (int Mt = 0; Mt < 4; ++Mt) {
      f32x4 d = relu4(o2a[Mt]);
      omax = fmaxf(omax, fmaxf(fmaxf(d[0], d[1]), fmaxf(d[2], d[3])));
    }
    __syncthreads();   // B4: o2 F-reads done before next stage-in
  }
  omax = fmaxf(omax, __shfl_xor(omax, 16));
  omax = fmaxf(omax, __shfl_xor(omax, 32));
  if (lane < 16)
    atomicMax(&out[b * 128 + w * 16 + lane], __float_as_uint(omax));
}

extern "C" void kernel_launch(void* const* d_in, const int* in_sizes, int n_in,
                              void* d_out, int out_size, void* d_ws, size_t ws_size,
                              hipStream_t stream) {
  const float* x    = (const float*)d_in[0];
  const int*   cls  = (const int*)d_in[1];
  const float* w_in = (const float*)d_in[2];
  const float* b_in = (const float*)d_in[3];
  const float* w1   = (const float*)d_in[4];
  const float* b1   = (const float*)d_in[5];
  const float* w2   = (const float*)d_in[6];
  const float* b2   = (const float*)d_in[7];
  const float* w3   = (const float*)d_in[8];
  const float* b3   = (const float*)d_in[9];
  const float* wo1  = (const float*)d_in[10];
  const float* bo1  = (const float*)d_in[11];
  const float* wo2  = (const float*)d_in[12];
  const float* bo2  = (const float*)d_in[13];

  char* ws = (char*)d_ws;
  unsigned* f3g = (unsigned*)ws;                            // 64 MB LDS image
  unsigned* part0 = (unsigned*)(ws + ((size_t)64 << 20));   // 3 x 8 KB
  unsigned* part1 = part0 + 8 * 2048;
  unsigned* part2 = part1 + 8 * 2048;
  float* poolc1 = (float*)(part2 + 8 * 2048);               // 8*1024
  float* poolc2 = poolc1 + 8 * 1024;
  float* poolco = poolc2 + 8 * 1024;                        // 8*2048
  unsigned* arena = (unsigned*)(poolco + 8 * 2048);         // 288*512 dwords

  hipMemsetAsync(d_out, 0, 1024 * sizeof(float), stream);
  hipMemsetAsync(part0, 0, 3 * 8 * 2048 * sizeof(unsigned), stream);

  prep_frags<<<N_UNITS, 64, 0, stream>>>(w_in, w1, w2, w3, wo1, wo2, arena);
  k0_kern<<<NBLK, TPB, 0, stream>>>(x, cls, b_in, b1, b2, b3, arena, f3g, part0);
  pool_reduce_kern<64><<<8, 1024, 0, stream>>>(part0, w1 + (size_t)64 * 256, b1 + 64, poolc1);
  kmid_kern<<<NBLK, TPB, 0, stream>>>(f3g, arena, poolc1, part1, cls, cls + NPTS,
                                      b2 + 128, b3 + 128, U_W1_1, U_W2_1, U_W3_1);
  pool_reduce_kern<64><<<8, 1024, 0, stream>>>(part1, w1 + (size_t)2 * 64 * 256, b1 + 128, poolc2);
  kmid_kern<<<NBLK, TPB, 0, stream>>>(f3g, arena, poolc2, part2, cls + NPTS, cls + 2 * NPTS,
                                      b2 + 256, b3 + 256, U_W1_2, U_W2_2, U_W3_2);
  pool_reduce_kern<128><<<8, 1024, 0, stream>>>(part2, wo1, bo1, poolco);
  k3_kern<<<NBLK, TPB, 0, stream>>>(f3g, arena, poolco, cls + 2 * NPTS, bo2, (unsigned*)d_out);
}